// Round 4
// baseline (232.702 us; speedup 1.0000x reference)
//
#include <hip/hip_runtime.h>

#define NQ     12
#define NPARAM 240       // 12*4*5
#define BLOCK  256
#define NREG   16

// State layout: global index g[11:0]; qubit q sits at bit P = 11 - q.
//   g[3:0]   = register index r (st[16] per lane, 32 VGPRs)
//   g[9:4]   = lane index within wave
//   g[11:10] = wave index (4 waves per block); tid = g[11:4]
// P < 4    -> register-class gate (static in-lane pairs)
// 4<=P<10  -> lane-class gate (DPP for xor1/2, shfl_xor for 4/8/16/32)
// P >= 10  -> wave-class gate (LDS exchange via conflict-free buf[r][tid])

template<int LM>
__device__ __forceinline__ float lxor(float v) {
    if constexpr (LM == 1) {        // quad_perm [1,0,3,2] = xor 1, VALU pipe
        return __int_as_float(__builtin_amdgcn_update_dpp(
            __float_as_int(v), __float_as_int(v), 0xB1, 0xF, 0xF, false));
    } else if constexpr (LM == 2) { // quad_perm [2,3,0,1] = xor 2, VALU pipe
        return __int_as_float(__builtin_amdgcn_update_dpp(
            __float_as_int(v), __float_as_int(v), 0x4E, 0xF, 0xF, false));
    } else {
        return __shfl_xor(v, LM, 64);
    }
}

__device__ __forceinline__ float2 cmulf(float2 a, float2 b) {
    return make_float2(a.x*b.x - a.y*b.y, a.x*b.y + a.y*b.x);
}

template<int P>
__device__ __forceinline__ void apply1q(float2* st, int tid,
                                        float2 (*buf)[BLOCK], const float* m) {
    float u00x=m[0],u00y=m[1],u01x=m[2],u01y=m[3];
    float u10x=m[4],u10y=m[5],u11x=m[6],u11y=m[7];
    if constexpr (P < 4) {
        #pragma unroll
        for (int r = 0; r < NREG; ++r) {
            if ((r >> P) & 1) continue;
            int r1 = r | (1 << P);
            float2 s0 = st[r], s1 = st[r1];
            st[r]  = make_float2(u00x*s0.x - u00y*s0.y + u01x*s1.x - u01y*s1.y,
                                 u00x*s0.y + u00y*s0.x + u01x*s1.y + u01y*s1.x);
            st[r1] = make_float2(u10x*s0.x - u10y*s0.y + u11x*s1.x - u11y*s1.y,
                                 u10x*s0.y + u10y*s0.x + u11x*s1.y + u11y*s1.x);
        }
    } else if constexpr (P < 10) {
        constexpr int LM = 1 << (P - 4);
        int bit = (tid >> (P - 4)) & 1;
        float uax = bit ? u11x : u00x, uay = bit ? u11y : u00y;
        float ubx = bit ? u10x : u01x, uby = bit ? u10y : u01y;
        #pragma unroll
        for (int r = 0; r < NREG; ++r) {
            float sx = st[r].x, sy = st[r].y;
            float ox = lxor<LM>(sx);
            float oy = lxor<LM>(sy);
            st[r] = make_float2(uax*sx - uay*sy + ubx*ox - uby*oy,
                                uax*sy + uay*sx + ubx*oy + uby*ox);
        }
    } else {
        constexpr int XM = 1 << (P - 4);       // 64 or 128 on tid
        int bit = (tid >> (P - 4)) & 1;
        float uax = bit ? u11x : u00x, uay = bit ? u11y : u00y;
        float ubx = bit ? u10x : u01x, uby = bit ? u10y : u01y;
        __syncthreads();                        // WAR vs prior buf reads
        #pragma unroll
        for (int r = 0; r < NREG; ++r) buf[r][tid] = st[r];
        __syncthreads();
        int pt = tid ^ XM;
        #pragma unroll
        for (int r = 0; r < NREG; ++r) {
            float2 o = buf[r][pt];
            float sx = st[r].x, sy = st[r].y;
            st[r] = make_float2(uax*sx - uay*sy + ubx*o.x - uby*o.y,
                                uax*sy + uay*sx + ubx*o.y + uby*o.x);
        }
    }
}

// CRX(ctrl bit PC, tgt bit PT): on ctrl=1 subspace apply RX: n = c*self - i*s*other
template<int PC, int PT>
__device__ __forceinline__ void applyCRX(float2* st, int tid,
                                         float2 (*buf)[BLOCK], const float* cs) {
    float c = cs[0], s = cs[1];
    if constexpr (PT < 4) {
        if constexpr (PC < 4) {
            #pragma unroll
            for (int r = 0; r < NREG; ++r) {
                if (!((r >> PC) & 1) || ((r >> PT) & 1)) continue;
                int r1 = r | (1 << PT);
                float2 s0 = st[r], s1 = st[r1];
                st[r]  = make_float2(c*s0.x + s*s1.y, c*s0.y - s*s1.x);
                st[r1] = make_float2(c*s1.x + s*s0.y, c*s1.y - s*s0.x);
            }
        } else {
            int apply = (tid >> (PC - 4)) & 1;
            float cc = apply ? c : 1.0f, ss = apply ? s : 0.0f;
            #pragma unroll
            for (int r = 0; r < NREG; ++r) {
                if ((r >> PT) & 1) continue;
                int r1 = r | (1 << PT);
                float2 s0 = st[r], s1 = st[r1];
                st[r]  = make_float2(cc*s0.x + ss*s1.y, cc*s0.y - ss*s1.x);
                st[r1] = make_float2(cc*s1.x + ss*s0.y, cc*s1.y - ss*s0.x);
            }
        }
    } else if constexpr (PT < 10) {
        constexpr int LM = 1 << (PT - 4);
        if constexpr (PC < 4) {
            #pragma unroll
            for (int r = 0; r < NREG; ++r) {
                if (!((r >> PC) & 1)) continue;
                float sx = st[r].x, sy = st[r].y;
                float ox = lxor<LM>(sx);
                float oy = lxor<LM>(sy);
                st[r] = make_float2(c*sx + s*oy, c*sy - s*ox);
            }
        } else {
            int apply = (tid >> (PC - 4)) & 1;
            float cc = apply ? c : 1.0f, ss = apply ? s : 0.0f;
            #pragma unroll
            for (int r = 0; r < NREG; ++r) {
                float sx = st[r].x, sy = st[r].y;
                float ox = lxor<LM>(sx);
                float oy = lxor<LM>(sy);
                st[r] = make_float2(cc*sx + ss*oy, cc*sy - ss*ox);
            }
        }
    } else {
        constexpr int XM = 1 << (PT - 4);
        if constexpr (PC < 4) {
            __syncthreads();
            #pragma unroll
            for (int r = 0; r < NREG; ++r)
                if ((r >> PC) & 1) buf[r][tid] = st[r];
            __syncthreads();
            int pt = tid ^ XM;
            #pragma unroll
            for (int r = 0; r < NREG; ++r) {
                if (!((r >> PC) & 1)) continue;
                float2 o = buf[r][pt];
                st[r] = make_float2(c*st[r].x + s*o.y, c*st[r].y - s*o.x);
            }
        } else {
            int apply = (tid >> (PC - 4)) & 1;
            float cc = apply ? c : 1.0f, ss = apply ? s : 0.0f;
            __syncthreads();
            #pragma unroll
            for (int r = 0; r < NREG; ++r) buf[r][tid] = st[r];
            __syncthreads();
            int pt = tid ^ XM;
            #pragma unroll
            for (int r = 0; r < NREG; ++r) {
                float2 o = buf[r][pt];
                st[r] = make_float2(cc*st[r].x + ss*o.y, cc*st[r].y - ss*o.x);
            }
        }
    }
}

template<int P>
__device__ __forceinline__ void expectq(const float2* st, int tid,
                                        float2 (*buf)[BLOCK],
                                        float& X, float& Y, float& Z) {
    float lx = 0.f, ly = 0.f, lz = 0.f;
    if constexpr (P < 4) {
        #pragma unroll
        for (int r = 0; r < NREG; ++r) {
            float2 a = st[r];
            float n = a.x*a.x + a.y*a.y;
            lz += ((r >> P) & 1) ? -n : n;
        }
        #pragma unroll
        for (int r = 0; r < NREG; ++r) {
            if ((r >> P) & 1) continue;
            int r1 = r | (1 << P);
            float2 s0 = st[r], s1 = st[r1];
            lx += s0.x*s1.x + s0.y*s1.y;
            ly += s0.x*s1.y - s0.y*s1.x;
        }
    } else if constexpr (P < 10) {
        constexpr int LM = 1 << (P - 4);
        int bit = (tid >> (P - 4)) & 1;
        float zs = bit ? -1.f : 1.f;
        float m  = bit ?  0.f : 1.f;
        #pragma unroll
        for (int r = 0; r < NREG; ++r) {
            float2 a = st[r];
            lz += zs * (a.x*a.x + a.y*a.y);
            float ox = lxor<LM>(a.x);
            float oy = lxor<LM>(a.y);
            lx += m * (a.x*ox + a.y*oy);
            ly += m * (a.x*oy - a.y*ox);
        }
    } else {
        constexpr int XM = 1 << (P - 4);
        int bit = (tid >> (P - 4)) & 1;
        float zs = bit ? -1.f : 1.f;
        float m  = bit ?  0.f : 1.f;
        __syncthreads();
        #pragma unroll
        for (int r = 0; r < NREG; ++r) buf[r][tid] = st[r];
        __syncthreads();
        int pt = tid ^ XM;
        #pragma unroll
        for (int r = 0; r < NREG; ++r) {
            float2 a = st[r];
            lz += zs * (a.x*a.x + a.y*a.y);
            float2 o = buf[r][pt];
            lx += m * (a.x*o.x + a.y*o.y);
            ly += m * (a.x*o.y - a.y*o.x);
        }
    }
    #pragma unroll
    for (int off = 32; off; off >>= 1) {
        lx += __shfl_xor(lx, off, 64);
        ly += __shfl_xor(ly, off, 64);
        lz += __shfl_xor(lz, off, 64);
    }
    X = 2.f*lx; Y = 2.f*ly; Z = lz;
}

__global__ __launch_bounds__(BLOCK, 4)
void qfe_kernel(const float* __restrict__ params,
                const float* __restrict__ inputs,
                float* __restrict__ out) {
    const int b    = blockIdx.x;
    const int tid  = threadIdx.x;
    const int lane = tid & 63;
    const int w    = tid >> 6;

    __shared__ float2 buf[NREG][BLOCK];   // 32 KB exchange buffer, conflict-free
    __shared__ float  m1[4 * 12 * 8];     // fused (Rz*Ry*Rx [*RYembed]) matrices
    __shared__ float  mcrx[4 * 24 * 2];
    __shared__ float  redbuf[4][36];

    if (tid < 48) {
        int l = tid / 12, q = tid % 12;
        const float* pp = params + b * NPARAM + l * 60 + q * 3;
        float ax = pp[0]*0.5f, ay = pp[1]*0.5f, az = pp[2]*0.5f;
        float cx = cosf(ax), sx = sinf(ax);
        float cy = cosf(ay), sy = sinf(ay);
        float cz = cosf(az), sz = sinf(az);
        float2 a00 = make_float2( cy*cx,  sy*sx);
        float2 a01 = make_float2(-sy*cx, -cy*sx);
        float2 a10 = make_float2( sy*cx, -cy*sx);
        float2 a11 = make_float2( cy*cx, -sy*sx);
        float2 e0 = make_float2(cz, -sz);
        float2 e1 = make_float2(cz,  sz);
        float2 u00 = cmulf(e0, a00), u01 = cmulf(e0, a01);
        float2 u10 = cmulf(e1, a10), u11 = cmulf(e1, a11);
        if (l == 0) {
            // fold RY input embedding: U = (Rz Ry Rx) * RY(e)
            float e = inputs[b * NQ + q] * 0.5f;
            float ce = cosf(e), se = sinf(e);
            float2 v00 = make_float2(u00.x*ce + u01.x*se, u00.y*ce + u01.y*se);
            float2 v01 = make_float2(-u00.x*se + u01.x*ce, -u00.y*se + u01.y*ce);
            float2 v10 = make_float2(u10.x*ce + u11.x*se, u10.y*ce + u11.y*se);
            float2 v11 = make_float2(-u10.x*se + u11.x*ce, -u10.y*se + u11.y*ce);
            u00 = v00; u01 = v01; u10 = v10; u11 = v11;
        }
        float* m = &m1[(l * 12 + q) * 8];
        m[0]=u00.x; m[1]=u00.y; m[2]=u01.x; m[3]=u01.y;
        m[4]=u10.x; m[5]=u10.y; m[6]=u11.x; m[7]=u11.y;
    }
    if (tid < 96) {
        int l = tid / 24, k = tid % 24;
        float a = params[b * NPARAM + l * 60 + 36 + k] * 0.5f;
        mcrx[(l * 24 + k) * 2]     = cosf(a);
        mcrx[(l * 24 + k) * 2 + 1] = sinf(a);
    }
    __syncthreads();

    float2 st[NREG];
    #pragma unroll
    for (int r = 0; r < NREG; ++r) st[r] = make_float2(0.f, 0.f);
    if (tid == 0) st[0] = make_float2(1.f, 0.f);

#define APPLY1Q(q) apply1q<11 - (q)>(st, tid, buf, ml + (q) * 8);
// ring1 step j: ctrl q=j (PC=11-j), tgt q=(j+1)%12 (PT=11-((j+1)%12))
#define R1(j) applyCRX<11 - (j), (11 - (((j) + 1) % 12))>(st, tid, buf, cl + (j) * 2);
// ring2 step k: ctrl q=11-k (PC=k), tgt=(10-k)%12 (PT=11-((22-k)%12))
#define R2(k) applyCRX<(k), (11 - ((22 - (k)) % 12))>(st, tid, buf, cl + (12 + (k)) * 2);

    #pragma unroll 1
    for (int l = 0; l < 4; ++l) {
        const float* ml = m1 + l * 96;
        const float* cl = mcrx + l * 48;
        APPLY1Q(0)  APPLY1Q(1)  APPLY1Q(2)  APPLY1Q(3)
        APPLY1Q(4)  APPLY1Q(5)  APPLY1Q(6)  APPLY1Q(7)
        APPLY1Q(8)  APPLY1Q(9)  APPLY1Q(10) APPLY1Q(11)
        R1(0)  R1(1)  R1(2)  R1(3)  R1(4)  R1(5)
        R1(6)  R1(7)  R1(8)  R1(9)  R1(10) R1(11)
        R2(0)  R2(1)  R2(2)  R2(3)  R2(4)  R2(5)
        R2(6)  R2(7)  R2(8)  R2(9)  R2(10) R2(11)
    }

#define EXPECT(q) { float X, Y, Z; expectq<11 - (q)>(st, tid, buf, X, Y, Z); \
                    if (lane == 0) { redbuf[w][(q)] = X; redbuf[w][12 + (q)] = Y; redbuf[w][24 + (q)] = Z; } }
    EXPECT(0)  EXPECT(1)  EXPECT(2)  EXPECT(3)
    EXPECT(4)  EXPECT(5)  EXPECT(6)  EXPECT(7)
    EXPECT(8)  EXPECT(9)  EXPECT(10) EXPECT(11)
    __syncthreads();
    if (tid < 36)
        out[b * 36 + tid] = redbuf[0][tid] + redbuf[1][tid] + redbuf[2][tid] + redbuf[3][tid];
}

extern "C" void kernel_launch(void* const* d_in, const int* in_sizes, int n_in,
                              void* d_out, int out_size, void* d_ws, size_t ws_size,
                              hipStream_t stream) {
    const float* params = (const float*)d_in[0];   // (1024, 240) float32
    const float* inputs = (const float*)d_in[1];   // (1024, 12)  float32
    float* out = (float*)d_out;                    // (1024, 36)  float32
    qfe_kernel<<<1024, BLOCK, 0, stream>>>(params, inputs, out);
}